// Round 1
// baseline (287.567 us; speedup 1.0000x reference)
//
#include <hip/hip_runtime.h>
#include <hip/hip_bf16.h>
#include <stdint.h>

// ---------- types ----------
typedef __attribute__((ext_vector_type(8))) short bf16x8;   // 8 bf16 in 4 VGPRs
typedef __attribute__((ext_vector_type(4))) float f32x4;

#define MFMA16(a, b, c) __builtin_amdgcn_mfma_f32_16x16x32_bf16(a, b, c, 0, 0, 0)

// async global->LDS, 16 bytes per lane; LDS dest = wave-uniform base + lane*16
typedef const __attribute__((address_space(1))) unsigned int* as1_u32p;
typedef __attribute__((address_space(3))) unsigned int* as3_u32p;
__device__ __forceinline__ void gl_lds16(const void* g, void* l) {
    __builtin_amdgcn_global_load_lds((as1_u32p)g, (as3_u32p)l, 16, 0, 0);
}

__device__ __forceinline__ unsigned short f2bs(float f) {
    __hip_bfloat16 h = __float2bfloat16(f);   // RNE
    unsigned short s;
    __builtin_memcpy(&s, &h, 2);
    return s;
}

// ---------- fp32 -> bf16 converts ----------
__global__ __launch_bounds__(256) void cvt_zt_k(const float* __restrict__ x,
                                                unsigned short* __restrict__ o) {
    int i = blockIdx.x * 256 + threadIdx.x;     // one float4 per thread
    const float4 v = ((const float4*)x)[i];
    ushort4 p;
    p.x = f2bs(v.x); p.y = f2bs(v.y); p.z = f2bs(v.z); p.w = f2bs(v.w);
    ((ushort4*)o)[i] = p;
}

__global__ __launch_bounds__(256) void cvt_w_k(const float* __restrict__ w,
                                               unsigned short* __restrict__ wbf,
                                               unsigned short* __restrict__ wtbf) {
    int i = blockIdx.x * 256 + threadIdx.x;     // 262144 threads
    int e = i >> 8;              // row 0..1023
    int d = (i & 255) << 2;      // col 0..1020
    const float4 v = *(const float4*)(w + e * 1024 + d);
    ushort4 p;
    p.x = f2bs(v.x); p.y = f2bs(v.y); p.z = f2bs(v.z); p.w = f2bs(v.w);
    *(ushort4*)(wbf + e * 1024 + d) = p;
    wtbf[(size_t)(d + 0) * 1024 + e] = p.x;
    wtbf[(size_t)(d + 1) * 1024 + e] = p.y;
    wtbf[(size_t)(d + 2) * 1024 + e] = p.z;
    wtbf[(size_t)(d + 3) * 1024 + e] = p.w;
}

// ---------- GEMM: C[M,N] = A[M,K] * B[N,K]^T  (m97 structure) ----------
// EPI 0: C -> ztu (b,h,n,dh) bf16 + ztut (b,h,dh,n) bf16     (M=4096,N=1024)
// EPI 1: C -> out0, out1 fp32                                 (M=4096,N=1024)
template <int EPI>
__global__ __launch_bounds__(256, 2) void gemm_bt_k(
    const __hip_bfloat16* __restrict__ A, const __hip_bfloat16* __restrict__ B, int K,
    __hip_bfloat16* __restrict__ ztu, __hip_bfloat16* __restrict__ ztut,
    float* __restrict__ out0, float* __restrict__ out1) {
    __shared__ __attribute__((aligned(16))) __hip_bfloat16 At[128 * 32];
    __shared__ __attribute__((aligned(16))) __hip_bfloat16 Bt[128 * 32];
    const int bn = blockIdx.x, bm = blockIdx.y;
    const int tid = threadIdx.x;
    const int wave = tid >> 6, lane = tid & 63;
    const int wm = wave >> 1, wn = wave & 1;   // 2x2 waves, each 64x64
    const int quad = lane >> 4, l16 = lane & 15;

    f32x4 acc[4][4] = {};

    // staging: 8 chunks of 1KB per tile; wave w does chunks {2w, 2w+1}
    const int c0 = wave * 2, c1 = c0 + 1;
    const int lr = lane >> 2, lc = (lane & 3) * 8;
    const __hip_bfloat16* Ag0 = A + (size_t)(bm * 128 + c0 * 16 + lr) * K + lc;
    const __hip_bfloat16* Ag1 = A + (size_t)(bm * 128 + c1 * 16 + lr) * K + lc;
    const __hip_bfloat16* Bg0 = B + (size_t)(bn * 128 + c0 * 16 + lr) * K + lc;
    const __hip_bfloat16* Bg1 = B + (size_t)(bn * 128 + c1 * 16 + lr) * K + lc;
    __hip_bfloat16* lA0 = &At[c0 * 512];
    __hip_bfloat16* lA1 = &At[c1 * 512];
    __hip_bfloat16* lB0 = &Bt[c0 * 512];
    __hip_bfloat16* lB1 = &Bt[c1 * 512];

    for (int kt = 0; kt < K; kt += 32) {
        gl_lds16(Ag0 + kt, lA0);
        gl_lds16(Ag1 + kt, lA1);
        gl_lds16(Bg0 + kt, lB0);
        gl_lds16(Bg1 + kt, lB1);
        __syncthreads();
        bf16x8 af[4], bfr[4];
#pragma unroll
        for (int i = 0; i < 4; ++i)
            af[i] = *(const bf16x8*)&At[(wm * 64 + i * 16 + l16) * 32 + quad * 8];
#pragma unroll
        for (int j = 0; j < 4; ++j)
            bfr[j] = *(const bf16x8*)&Bt[(wn * 64 + j * 16 + l16) * 32 + quad * 8];
#pragma unroll
        for (int i = 0; i < 4; ++i)
#pragma unroll
            for (int j = 0; j < 4; ++j) acc[i][j] = MFMA16(af[i], bfr[j], acc[i][j]);
        __syncthreads();
    }

    if (EPI == 0) {
#pragma unroll
        for (int i = 0; i < 4; ++i) {
#pragma unroll
            for (int r = 0; r < 4; ++r) {
                const int mm = bm * 128 + wm * 64 + i * 16 + quad * 4 + r;  // token
                const int b = mm >> 11, n = mm & 2047;
#pragma unroll
                for (int j = 0; j < 4; ++j) {
                    const int e = bn * 128 + wn * 64 + j * 16 + l16;
                    const int h = e >> 6, dh = e & 63;
                    const int bh = b * 16 + h;
                    __hip_bfloat16 v = __float2bfloat16(acc[i][j][r]);
                    ztu[(size_t)bh * 131072 + n * 64 + dh] = v;
                    ztut[(size_t)bh * 131072 + dh * 2048 + n] = v;
                }
            }
        }
    } else {
#pragma unroll
        for (int i = 0; i < 4; ++i) {
#pragma unroll
            for (int r = 0; r < 4; ++r) {
                const int mm = bm * 128 + wm * 64 + i * 16 + quad * 4 + r;
#pragma unroll
                for (int j = 0; j < 4; ++j) {
                    const int e = bn * 128 + wn * 64 + j * 16 + l16;
                    const float v = acc[i][j][r];
                    out0[(size_t)mm * 1024 + e] = v;
                    out1[(size_t)mm * 1024 + e] = v;
                }
            }
        }
    }
}

// ---------- flash attention: Q=K=V = ztu[bh] (2048x64), scale 0.125 ----------
// grid (32 qtiles, 32 bh), 256 threads = 4 waves, each wave owns 16 q-rows.
__global__ __launch_bounds__(256, 4) void attn_k(const __hip_bfloat16* __restrict__ ztu,
                                                 const __hip_bfloat16* __restrict__ ztut,
                                                 __hip_bfloat16* __restrict__ ssa) {
    __shared__ __attribute__((aligned(16))) __hip_bfloat16 Kt[64 * 64];     // [key][d]
    __shared__ __attribute__((aligned(16))) __hip_bfloat16 Vt[64 * 64];     // [d][key]
    __shared__ __attribute__((aligned(16))) __hip_bfloat16 Pt[4][16 * 72];  // per-wave P, padded
    const int qt = blockIdx.x, bh = blockIdx.y;
    const int tid = threadIdx.x, wave = tid >> 6, lane = tid & 63;
    const int quad = lane >> 4, l16 = lane & 15;
    const __hip_bfloat16* base = ztu + (size_t)bh * 131072;
    const __hip_bfloat16* baseT = ztut + (size_t)bh * 131072;

    // Q fragments (A-layout: m=l16, k=quad*8+j), pre-scaled by 1/8 (exact in bf16)
    const int qrow = qt * 64 + wave * 16 + l16;
    bf16x8 qa0 = *(const bf16x8*)(base + qrow * 64 + quad * 8);
    bf16x8 qa1 = *(const bf16x8*)(base + qrow * 64 + 32 + quad * 8);
#pragma unroll
    for (int j = 0; j < 8; ++j) {
        float f0 = __uint_as_float(((unsigned)(unsigned short)qa0[j]) << 16) * 0.125f;
        float f1 = __uint_as_float(((unsigned)(unsigned short)qa1[j]) << 16) * 0.125f;
        qa0[j] = (short)(__float_as_uint(f0) >> 16);
        qa1[j] = (short)(__float_as_uint(f1) >> 16);
    }

    float m_r[4], l_r[4];
    f32x4 o[4] = {};
#pragma unroll
    for (int r = 0; r < 4; ++r) { m_r[r] = -1e30f; l_r[r] = 0.f; }

    // staging addresses (chunks 2w, 2w+1 per wave for each tile)
    const int c0 = wave * 2, c1 = c0 + 1;
    const __hip_bfloat16* gK0 = base + c0 * 512 + lane * 8;                       // K tile contiguous 8KB
    const __hip_bfloat16* gK1 = base + c1 * 512 + lane * 8;
    const __hip_bfloat16* gV0 = baseT + (size_t)(c0 * 8 + (lane >> 3)) * 2048 + (lane & 7) * 8;
    const __hip_bfloat16* gV1 = baseT + (size_t)(c1 * 8 + (lane >> 3)) * 2048 + (lane & 7) * 8;
    __hip_bfloat16* lK0 = &Kt[c0 * 512];
    __hip_bfloat16* lK1 = &Kt[c1 * 512];
    __hip_bfloat16* lV0 = &Vt[c0 * 512];
    __hip_bfloat16* lV1 = &Vt[c1 * 512];
    __hip_bfloat16* pw = &Pt[wave][0];

    for (int t = 0; t < 32; ++t) {
        gl_lds16(gK0 + t * 4096, lK0);
        gl_lds16(gK1 + t * 4096, lK1);
        gl_lds16(gV0 + t * 64, lV0);
        gl_lds16(gV1 + t * 64, lV1);
        __syncthreads();

        // S = Qs * K^T   (16 x 64), C-layout: col(key)=l16, row(q)=quad*4+r
        f32x4 s[4];
#pragma unroll
        for (int nf = 0; nf < 4; ++nf) {
            bf16x8 kb0 = *(const bf16x8*)&Kt[(nf * 16 + l16) * 64 + quad * 8];
            bf16x8 kb1 = *(const bf16x8*)&Kt[(nf * 16 + l16) * 64 + 32 + quad * 8];
            f32x4 z = {0.f, 0.f, 0.f, 0.f};
            z = MFMA16(qa0, kb0, z);
            z = MFMA16(qa1, kb1, z);
            s[nf] = z;
        }

        // online softmax (fp32)
#pragma unroll
        for (int r = 0; r < 4; ++r) {
            float mx = fmaxf(fmaxf(s[0][r], s[1][r]), fmaxf(s[2][r], s[3][r]));
            mx = fmaxf(mx, __shfl_xor(mx, 1));
            mx = fmaxf(mx, __shfl_xor(mx, 2));
            mx = fmaxf(mx, __shfl_xor(mx, 4));
            mx = fmaxf(mx, __shfl_xor(mx, 8));
            const float mnew = fmaxf(m_r[r], mx);
            const float alpha = exp2f((m_r[r] - mnew) * 1.44269504f);
            m_r[r] = mnew;
            float ps = 0.f;
#pragma unroll
            for (int nf = 0; nf < 4; ++nf) {
                float p = exp2f((s[nf][r] - mnew) * 1.44269504f);
                s[nf][r] = p;
                ps += p;
            }
            ps += __shfl_xor(ps, 1);
            ps += __shfl_xor(ps, 2);
            ps += __shfl_xor(ps, 4);
            ps += __shfl_xor(ps, 8);
            l_r[r] = l_r[r] * alpha + ps;
            o[0][r] *= alpha;
            o[1][r] *= alpha;
            o[2][r] *= alpha;
            o[3][r] *= alpha;
        }

        // P: C-layout -> A-layout via per-wave LDS (bf16), padded stride 72
#pragma unroll
        for (int nf = 0; nf < 4; ++nf)
#pragma unroll
            for (int r = 0; r < 4; ++r)
                pw[(quad * 4 + r) * 72 + nf * 16 + l16] = __float2bfloat16(s[nf][r]);
        asm volatile("s_waitcnt lgkmcnt(0)" ::: "memory");
        bf16x8 pa0 = *(const bf16x8*)&pw[l16 * 72 + quad * 8];
        bf16x8 pa1 = *(const bf16x8*)&pw[l16 * 72 + 32 + quad * 8];

        // O += P * V  (B-frag from Vt: B[k=key][n=d] = Vt[d][key])
#pragma unroll
        for (int df = 0; df < 4; ++df) {
            bf16x8 vb0 = *(const bf16x8*)&Vt[(df * 16 + l16) * 64 + quad * 8];
            bf16x8 vb1 = *(const bf16x8*)&Vt[(df * 16 + l16) * 64 + 32 + quad * 8];
            o[df] = MFMA16(pa0, vb0, o[df]);
            o[df] = MFMA16(pa1, vb1, o[df]);
        }
        __syncthreads();
    }

    // epilogue: ssa[token][h*64+d] bf16
    const int b = bh >> 4, h = bh & 15;
#pragma unroll
    for (int df = 0; df < 4; ++df) {
#pragma unroll
        for (int r = 0; r < 4; ++r) {
            const float v = o[df][r] / l_r[r];
            const int q = qt * 64 + wave * 16 + quad * 4 + r;
            const int token = b * 2048 + q;
            ssa[(size_t)token * 1024 + h * 64 + df * 16 + l16] = __float2bfloat16(v);
        }
    }
}

// ---------- launch ----------
extern "C" void kernel_launch(void* const* d_in, const int* in_sizes, int n_in,
                              void* d_out, int out_size, void* d_ws, size_t ws_size,
                              hipStream_t stream) {
    const float* ZT = (const float*)d_in[0];  // (2,2048,1024)
    const float* W = (const float*)d_in[1];   // (1024,1024)
    float* out = (float*)d_out;               // 2 x 4194304 fp32
    char* ws = (char*)d_ws;

    __hip_bfloat16* ztbf  = (__hip_bfloat16*)(ws);                       // 8 MB
    __hip_bfloat16* wbf   = (__hip_bfloat16*)(ws + 8u * 1024 * 1024);    // 2 MB
    __hip_bfloat16* wtbf  = (__hip_bfloat16*)(ws + 10u * 1024 * 1024);   // 2 MB
    __hip_bfloat16* ztu   = (__hip_bfloat16*)(ws + 12u * 1024 * 1024);   // 8 MB (b,h,n,dh)
    __hip_bfloat16* ztut  = (__hip_bfloat16*)(ws + 20u * 1024 * 1024);   // 8 MB (b,h,dh,n)
    __hip_bfloat16* ssabf = (__hip_bfloat16*)(ws + 28u * 1024 * 1024);   // 8 MB

    cvt_zt_k<<<4096, 256, 0, stream>>>(ZT, (unsigned short*)ztbf);
    cvt_w_k<<<1024, 256, 0, stream>>>(W, (unsigned short*)wbf, (unsigned short*)wtbf);
    // ZTU = ZT @ W^T  -> (b,h,n,dh) and (b,h,dh,n)
    gemm_bt_k<0><<<dim3(8, 32), 256, 0, stream>>>(ztbf, wbf, 1024, ztu, ztut, nullptr, nullptr);
    // flash attention per (bh, qtile)
    attn_k<<<dim3(32, 32), 256, 0, stream>>>(ztu, ztut, ssabf);
    // mssa = ssa @ W  (B = W^T in NxK form), duplicated output
    gemm_bt_k<1><<<dim3(8, 32), 256, 0, stream>>>(ssabf, wtbf, 1024, nullptr, nullptr, out,
                                                  out + 4194304);
}

// Round 2
// 205.410 us; speedup vs baseline: 1.4000x; 1.4000x over previous
//
#include <hip/hip_runtime.h>
#include <hip/hip_bf16.h>
#include <stdint.h>

// ---------- types ----------
typedef __attribute__((ext_vector_type(8))) short bf16x8;   // 8 bf16 in 4 VGPRs
typedef __attribute__((ext_vector_type(4))) float f32x4;

#define MFMA16(a, b, c) __builtin_amdgcn_mfma_f32_16x16x32_bf16(a, b, c, 0, 0, 0)

// async global->LDS, 16 bytes per lane; LDS dest = wave-uniform base + lane*16
typedef const __attribute__((address_space(1))) unsigned int* as1_u32p;
typedef __attribute__((address_space(3))) unsigned int* as3_u32p;
__device__ __forceinline__ void gl_lds16(const void* g, void* l) {
    __builtin_amdgcn_global_load_lds((as1_u32p)g, (as3_u32p)l, 16, 0, 0);
}

__device__ __forceinline__ unsigned short f2bs(float f) {
    __hip_bfloat16 h = __float2bfloat16(f);   // RNE
    unsigned short s;
    __builtin_memcpy(&s, &h, 2);
    return s;
}

// combined softmax scale: DH^-0.5 * log2(e) -> scores come out in log2 domain
#define QSCALE 0.18033688f

// ---------- fp32 -> bf16 converts ----------
__global__ __launch_bounds__(256) void cvt_zt_k(const float* __restrict__ x,
                                                unsigned short* __restrict__ o) {
    int i = blockIdx.x * 256 + threadIdx.x;     // one float4 per thread
    const float4 v = ((const float4*)x)[i];
    ushort4 p;
    p.x = f2bs(v.x); p.y = f2bs(v.y); p.z = f2bs(v.z); p.w = f2bs(v.w);
    ((ushort4*)o)[i] = p;
}

// wtbf stored with K-dim (e) permuted within 64-blocks: e_store = 4*(e&15) + ((e>>4)&3)
// (matches the ssa storage permutation so GEMM2 dot-products stay aligned)
__global__ __launch_bounds__(256) void cvt_w_k(const float* __restrict__ w,
                                               unsigned short* __restrict__ wbf,
                                               unsigned short* __restrict__ wtbf) {
    int i = blockIdx.x * 256 + threadIdx.x;     // 262144 threads
    int e = i >> 8;              // W row 0..1023
    int d = (i & 255) << 2;      // col 0..1020
    const float4 v = *(const float4*)(w + e * 1024 + d);
    ushort4 p;
    p.x = f2bs(v.x); p.y = f2bs(v.y); p.z = f2bs(v.z); p.w = f2bs(v.w);
    *(ushort4*)(wbf + e * 1024 + d) = p;
    const int ep = (e & ~63) | (4 * (e & 15) + ((e >> 4) & 3));
    wtbf[(size_t)(d + 0) * 1024 + ep] = p.x;
    wtbf[(size_t)(d + 1) * 1024 + ep] = p.y;
    wtbf[(size_t)(d + 2) * 1024 + ep] = p.z;
    wtbf[(size_t)(d + 3) * 1024 + ep] = p.w;
}

// ---------- GEMM: C[M,N] = A[M,K] * B[N,K]^T  (m97 structure) ----------
// EPI 0: C -> ztu (b,h,n,dh_perm) bf16 [packed b64] + ztut (b,h,dh,n_perm) bf16
// EPI 1: C -> out0, out1 fp32
template <int EPI>
__global__ __launch_bounds__(256, 2) void gemm_bt_k(
    const __hip_bfloat16* __restrict__ A, const __hip_bfloat16* __restrict__ B, int K,
    unsigned short* __restrict__ ztu, unsigned short* __restrict__ ztut,
    float* __restrict__ out0, float* __restrict__ out1) {
    __shared__ __attribute__((aligned(16))) __hip_bfloat16 At[128 * 32];
    __shared__ __attribute__((aligned(16))) __hip_bfloat16 Bt[128 * 32];
    const int bn = blockIdx.x, bm = blockIdx.y;
    const int tid = threadIdx.x;
    const int wave = tid >> 6, lane = tid & 63;
    const int wm = wave >> 1, wn = wave & 1;   // 2x2 waves, each 64x64
    const int quad = lane >> 4, l16 = lane & 15;

    f32x4 acc[4][4] = {};

    const int c0 = wave * 2, c1 = c0 + 1;
    const int lr = lane >> 2, lc = (lane & 3) * 8;
    const __hip_bfloat16* Ag0 = A + (size_t)(bm * 128 + c0 * 16 + lr) * K + lc;
    const __hip_bfloat16* Ag1 = A + (size_t)(bm * 128 + c1 * 16 + lr) * K + lc;
    const __hip_bfloat16* Bg0 = B + (size_t)(bn * 128 + c0 * 16 + lr) * K + lc;
    const __hip_bfloat16* Bg1 = B + (size_t)(bn * 128 + c1 * 16 + lr) * K + lc;
    __hip_bfloat16* lA0 = &At[c0 * 512];
    __hip_bfloat16* lA1 = &At[c1 * 512];
    __hip_bfloat16* lB0 = &Bt[c0 * 512];
    __hip_bfloat16* lB1 = &Bt[c1 * 512];

    for (int kt = 0; kt < K; kt += 32) {
        gl_lds16(Ag0 + kt, lA0);
        gl_lds16(Ag1 + kt, lA1);
        gl_lds16(Bg0 + kt, lB0);
        gl_lds16(Bg1 + kt, lB1);
        __syncthreads();
        bf16x8 af[4], bfr[4];
#pragma unroll
        for (int i = 0; i < 4; ++i)
            af[i] = *(const bf16x8*)&At[(wm * 64 + i * 16 + l16) * 32 + quad * 8];
#pragma unroll
        for (int j = 0; j < 4; ++j)
            bfr[j] = *(const bf16x8*)&Bt[(wn * 64 + j * 16 + l16) * 32 + quad * 8];
#pragma unroll
        for (int i = 0; i < 4; ++i)
#pragma unroll
            for (int j = 0; j < 4; ++j) acc[i][j] = MFMA16(af[i], bfr[j], acc[i][j]);
        __syncthreads();
    }

    if (EPI == 0) {
        const int h = bn * 2 + wn;   // j*16+l16 < 64, so h is j-independent
#pragma unroll
        for (int i = 0; i < 4; ++i) {
#pragma unroll
            for (int r = 0; r < 4; ++r) {
                const int mm = bm * 128 + wm * 64 + i * 16 + quad * 4 + r;  // token
                const int b = mm >> 11, n = mm & 2047;
                const size_t hb = (size_t)(b * 16 + h) * 131072;
                ushort4 pk;
                pk.x = f2bs(acc[i][0][r]);
                pk.y = f2bs(acc[i][1][r]);
                pk.z = f2bs(acc[i][2][r]);
                pk.w = f2bs(acc[i][3][r]);
                // ztu: dh stored-permuted (4*l16 + j) -> one packed b64 store
                *(ushort4*)(ztu + hb + n * 64 + l16 * 4) = pk;
                // ztut: rows = natural dh, cols = n permuted within 64-blocks
                const int np = (n & ~63) | (4 * (n & 15) + ((n >> 4) & 3));
                unsigned short* zt = ztut + hb + np;
                zt[(size_t)(0 * 16 + l16) * 2048] = pk.x;
                zt[(size_t)(1 * 16 + l16) * 2048] = pk.y;
                zt[(size_t)(2 * 16 + l16) * 2048] = pk.z;
                zt[(size_t)(3 * 16 + l16) * 2048] = pk.w;
            }
        }
    } else {
#pragma unroll
        for (int i = 0; i < 4; ++i) {
#pragma unroll
            for (int r = 0; r < 4; ++r) {
                const int mm = bm * 128 + wm * 64 + i * 16 + quad * 4 + r;
#pragma unroll
                for (int j = 0; j < 4; ++j) {
                    const int e = bn * 128 + wn * 64 + j * 16 + l16;
                    const float v = acc[i][j][r];
                    out0[(size_t)mm * 1024 + e] = v;
                    out1[(size_t)mm * 1024 + e] = v;
                }
            }
        }
    }
}

// ---------- flash attention ----------
// grid (16 qtiles, 32 bh), 256 threads = 4 waves; each wave owns 32 q-rows (2 groups of 16).
// K/V LDS tiles XOR-swizzled (chunk ^ row&7) -> conflict-free b128 reads.
// Softmax: fixed max (scores in log2 domain via QSCALE), per-lane partial sums,
// single cross-lane reduction in the epilogue.
__global__ __launch_bounds__(256, 2) void attn_k(const unsigned short* __restrict__ ztu,
                                                 const unsigned short* __restrict__ ztut,
                                                 unsigned short* __restrict__ ssa) {
    __shared__ __attribute__((aligned(16))) unsigned short Kt[64 * 64];   // [key][d-swizzled]
    __shared__ __attribute__((aligned(16))) unsigned short Vt[64 * 64];   // [d][key-swizzled]
    __shared__ __attribute__((aligned(16))) unsigned short Pt[4][32 * 72];  // per-wave P
    const int qt = blockIdx.x, bh = blockIdx.y;
    const int tid = threadIdx.x, wave = tid >> 6, lane = tid & 63;
    const int quad = lane >> 4, l16 = lane & 15;
    const unsigned short* base = ztu + (size_t)bh * 131072;
    const unsigned short* baseT = ztut + (size_t)bh * 131072;

    // Q fragments: 2 row-groups x 2 k-chunks, pre-scaled by DH^-0.5 * log2(e)
    const int qb = qt * 128 + wave * 32;
    bf16x8 qa[2][2];
#pragma unroll
    for (int g = 0; g < 2; ++g) {
        qa[g][0] = *(const bf16x8*)(base + (qb + g * 16 + l16) * 64 + quad * 8);
        qa[g][1] = *(const bf16x8*)(base + (qb + g * 16 + l16) * 64 + 32 + quad * 8);
#pragma unroll
        for (int j = 0; j < 8; ++j) {
            float f0 = __uint_as_float(((unsigned)(unsigned short)qa[g][0][j]) << 16) * QSCALE;
            float f1 = __uint_as_float(((unsigned)(unsigned short)qa[g][1][j]) << 16) * QSCALE;
            qa[g][0][j] = (short)(__float_as_uint(f0) >> 16);
            qa[g][1][j] = (short)(__float_as_uint(f1) >> 16);
        }
    }

    float lsum[2][4] = {};
    f32x4 o[2][4] = {};

    // staging: tile = 8 chunks of 1KB; wave w stages chunks {2w,2w+1} of K and V.
    // chunk c covers rows c*8+(lane>>3); swizzled source chunk = (lane&7)^(lane>>3)
    const int c0 = wave * 2, c1 = c0 + 1;
    const int lrow = lane >> 3;
    const int sw = (lane & 7) ^ lrow;
    const unsigned short* gK0 = base + (c0 * 8 + lrow) * 64 + sw * 8;
    const unsigned short* gK1 = base + (c1 * 8 + lrow) * 64 + sw * 8;
    const unsigned short* gV0 = baseT + (size_t)(c0 * 8 + lrow) * 2048 + sw * 8;
    const unsigned short* gV1 = baseT + (size_t)(c1 * 8 + lrow) * 2048 + sw * 8;
    unsigned short* lK0 = &Kt[c0 * 512];
    unsigned short* lK1 = &Kt[c1 * 512];
    unsigned short* lV0 = &Vt[c0 * 512];
    unsigned short* lV1 = &Vt[c1 * 512];
    unsigned short* pw = &Pt[wave][0];

    // swizzled read offsets (elements): row l16 within a 16-row group, chunk quad
    const int swq = (quad ^ (l16 & 7));
    const int koff0 = l16 * 64 + swq * 8;          // + nf*1024 (rows) per fragment
    const int koff1 = l16 * 64 + (swq ^ 4) * 8;

    for (int t = 0; t < 32; ++t) {
        gl_lds16(gK0 + t * 4096, lK0);
        gl_lds16(gK1 + t * 4096, lK1);
        gl_lds16(gV0 + t * 64, lV0);
        gl_lds16(gV1 + t * 64, lV1);
        __syncthreads();

        // S = Qs * K^T  (32 q x 64 keys), C-layout col(key)=l16, row(q)=quad*4+r
        f32x4 s[2][4];
#pragma unroll
        for (int nf = 0; nf < 4; ++nf) {
            bf16x8 kb0 = *(const bf16x8*)&Kt[nf * 1024 + koff0];
            bf16x8 kb1 = *(const bf16x8*)&Kt[nf * 1024 + koff1];
#pragma unroll
            for (int g = 0; g < 2; ++g) {
                f32x4 z = {0.f, 0.f, 0.f, 0.f};
                z = MFMA16(qa[g][0], kb0, z);
                z = MFMA16(qa[g][1], kb1, z);
                s[g][nf] = z;
            }
        }

        // p = exp2(s); accumulate per-lane partial sums; pack 4 bf16 -> b64 LDS write.
        // P stored col = 4*l16 + nf  (matches ztut's key permutation)
#pragma unroll
        for (int g = 0; g < 2; ++g) {
#pragma unroll
            for (int r = 0; r < 4; ++r) {
                const float p0 = exp2f(s[g][0][r]);
                const float p1 = exp2f(s[g][1][r]);
                const float p2 = exp2f(s[g][2][r]);
                const float p3 = exp2f(s[g][3][r]);
                lsum[g][r] += (p0 + p1) + (p2 + p3);
                ushort4 pk;
                pk.x = f2bs(p0); pk.y = f2bs(p1); pk.z = f2bs(p2); pk.w = f2bs(p3);
                *(ushort4*)&pw[(g * 16 + quad * 4 + r) * 72 + l16 * 4] = pk;
            }
        }
        asm volatile("s_waitcnt lgkmcnt(0)" ::: "memory");

        // O += P * V   (B-frag rows = d, swizzled key chunks)
        bf16x8 pa[2][2];
#pragma unroll
        for (int g = 0; g < 2; ++g) {
            pa[g][0] = *(const bf16x8*)&pw[(g * 16 + l16) * 72 + quad * 8];
            pa[g][1] = *(const bf16x8*)&pw[(g * 16 + l16) * 72 + 32 + quad * 8];
        }
#pragma unroll
        for (int df = 0; df < 4; ++df) {
            bf16x8 vb0 = *(const bf16x8*)&Vt[df * 1024 + koff0];
            bf16x8 vb1 = *(const bf16x8*)&Vt[df * 1024 + koff1];
#pragma unroll
            for (int g = 0; g < 2; ++g) {
                o[g][df] = MFMA16(pa[g][0], vb0, o[g][df]);
                o[g][df] = MFMA16(pa[g][1], vb1, o[g][df]);
            }
        }
        __syncthreads();
    }

    // epilogue: reduce l across the 16 key-lanes, then packed b64 stores.
    // ssa stored col = h*64 + 4*l16 + df  (matches wtbf's e permutation)
    const int b = bh >> 4, h = bh & 15;
#pragma unroll
    for (int g = 0; g < 2; ++g) {
#pragma unroll
        for (int r = 0; r < 4; ++r) {
            float v = lsum[g][r];
            v += __shfl_xor(v, 1);
            v += __shfl_xor(v, 2);
            v += __shfl_xor(v, 4);
            v += __shfl_xor(v, 8);
            const float inv = 1.0f / v;
            const int token = b * 2048 + qt * 128 + wave * 32 + g * 16 + quad * 4 + r;
            ushort4 pk;
            pk.x = f2bs(o[g][0][r] * inv);
            pk.y = f2bs(o[g][1][r] * inv);
            pk.z = f2bs(o[g][2][r] * inv);
            pk.w = f2bs(o[g][3][r] * inv);
            *(ushort4*)(ssa + (size_t)token * 1024 + h * 64 + l16 * 4) = pk;
        }
    }
}

// ---------- launch ----------
extern "C" void kernel_launch(void* const* d_in, const int* in_sizes, int n_in,
                              void* d_out, int out_size, void* d_ws, size_t ws_size,
                              hipStream_t stream) {
    const float* ZT = (const float*)d_in[0];  // (2,2048,1024)
    const float* W = (const float*)d_in[1];   // (1024,1024)
    float* out = (float*)d_out;               // 2 x 4194304 fp32
    char* ws = (char*)d_ws;

    unsigned short* ztbf  = (unsigned short*)(ws);                       // 8 MB
    unsigned short* wbf   = (unsigned short*)(ws + 8u * 1024 * 1024);    // 2 MB
    unsigned short* wtbf  = (unsigned short*)(ws + 10u * 1024 * 1024);   // 2 MB
    unsigned short* ztu   = (unsigned short*)(ws + 12u * 1024 * 1024);   // 8 MB (b,h,n,dh_perm)
    unsigned short* ztut  = (unsigned short*)(ws + 20u * 1024 * 1024);   // 8 MB (b,h,dh,n_perm)
    unsigned short* ssabf = (unsigned short*)(ws + 28u * 1024 * 1024);   // 8 MB (e_perm)

    cvt_zt_k<<<4096, 256, 0, stream>>>(ZT, ztbf);
    cvt_w_k<<<1024, 256, 0, stream>>>(W, wbf, wtbf);
    // ZTU = ZT @ W^T
    gemm_bt_k<0><<<dim3(8, 32), 256, 0, stream>>>((const __hip_bfloat16*)ztbf,
                                                  (const __hip_bfloat16*)wbf, 1024, ztu, ztut,
                                                  nullptr, nullptr);
    // flash attention per (bh, qtile of 128 rows)
    attn_k<<<dim3(16, 32), 256, 0, stream>>>(ztu, ztut, ssabf);
    // mssa = ssa @ W, duplicated output
    gemm_bt_k<1><<<dim3(8, 32), 256, 0, stream>>>((const __hip_bfloat16*)ssabf,
                                                  (const __hip_bfloat16*)wtbf, 1024, nullptr,
                                                  nullptr, out, out + 4194304);
}

// Round 3
// 183.754 us; speedup vs baseline: 1.5650x; 1.1179x over previous
//
#include <hip/hip_runtime.h>
#include <hip/hip_bf16.h>
#include <stdint.h>

// ---------- types ----------
typedef __attribute__((ext_vector_type(8))) short bf16x8;   // 8 bf16 in 4 VGPRs
typedef __attribute__((ext_vector_type(4))) float f32x4;

#define MFMA16(a, b, c) __builtin_amdgcn_mfma_f32_16x16x32_bf16(a, b, c, 0, 0, 0)

// async global->LDS, 16 bytes per lane; LDS dest = wave-uniform base + lane*16
typedef const __attribute__((address_space(1))) unsigned int* as1_u32p;
typedef __attribute__((address_space(3))) unsigned int* as3_u32p;
__device__ __forceinline__ void gl_lds16(const void* g, void* l) {
    __builtin_amdgcn_global_load_lds((as1_u32p)g, (as3_u32p)l, 16, 0, 0);
}

__device__ __forceinline__ unsigned short f2bs(float f) {
    __hip_bfloat16 h = __float2bfloat16(f);   // RNE
    unsigned short s;
    __builtin_memcpy(&s, &h, 2);
    return s;
}

// packed RNE f32x2 -> bf16x2 (v_cvt_pk_bf16_f32 on gfx950)
__device__ __forceinline__ unsigned int pk_bf16(float a, float b) {
    float2 f; f.x = a; f.y = b;
    __hip_bfloat162 h = __float22bfloat162_rn(f);
    unsigned int u;
    __builtin_memcpy(&u, &h, 4);
    return u;
}

// raw v_exp_f32: D = 2^S0 (softmax inputs are well in range; flush-to-zero ok)
__device__ __forceinline__ float exp2_raw(float x) {
    float r;
    asm("v_exp_f32 %0, %1" : "=v"(r) : "v"(x));
    return r;
}

// combined softmax scale: DH^-0.5 * log2(e); applied to fp32 scores pre-exp
#define QSCALE 0.18033688f

// ---------- fp32 -> bf16 converts (merged: blocks [0,4096) ZT, [4096,5120) W) ----------
__global__ __launch_bounds__(256) void cvt_k(const float* __restrict__ zt,
                                             const float* __restrict__ w,
                                             unsigned short* __restrict__ ztbf,
                                             unsigned short* __restrict__ wbf,
                                             unsigned short* __restrict__ wtbf) {
    const int bid = blockIdx.x;
    if (bid < 4096) {
        int i = bid * 256 + threadIdx.x;     // one float4 per thread
        const float4 v = ((const float4*)zt)[i];
        ushort4 p;
        p.x = f2bs(v.x); p.y = f2bs(v.y); p.z = f2bs(v.z); p.w = f2bs(v.w);
        ((ushort4*)ztbf)[i] = p;
    } else {
        int i = (bid - 4096) * 256 + threadIdx.x;
        int e = i >> 8;              // W row 0..1023
        int d = (i & 255) << 2;      // col 0..1020
        const float4 v = *(const float4*)(w + e * 1024 + d);
        ushort4 p;
        p.x = f2bs(v.x); p.y = f2bs(v.y); p.z = f2bs(v.z); p.w = f2bs(v.w);
        *(ushort4*)(wbf + e * 1024 + d) = p;
        // wtbf: K-dim (e) permuted within 64-blocks to match ssa's storage perm
        const int ep = (e & ~63) | (4 * (e & 15) + ((e >> 4) & 3));
        wtbf[(size_t)(d + 0) * 1024 + ep] = p.x;
        wtbf[(size_t)(d + 1) * 1024 + ep] = p.y;
        wtbf[(size_t)(d + 2) * 1024 + ep] = p.z;
        wtbf[(size_t)(d + 3) * 1024 + ep] = p.w;
    }
}

// ---------- GEMM: C[M,N] = A[M,K] * B[N,K]^T, tile 64x128, 4 waves ----------
// grid (8, M/64) -> 512 blocks = 2 blocks/CU so barrier drains overlap across blocks.
// EPI 0: C -> ztu (b,h,n,dh_perm) bf16 [packed b64] + ztut (b,h,dh,n_perm) bf16
// EPI 1: C -> out0, out1 fp32
template <int EPI>
__global__ __launch_bounds__(256, 4) void gemm_bt_k(
    const __hip_bfloat16* __restrict__ A, const __hip_bfloat16* __restrict__ B, int K,
    unsigned short* __restrict__ ztu, unsigned short* __restrict__ ztut,
    float* __restrict__ out0, float* __restrict__ out1) {
    __shared__ __attribute__((aligned(16))) __hip_bfloat16 At[64 * 32];    // 4 KB
    __shared__ __attribute__((aligned(16))) __hip_bfloat16 Bt[128 * 32];   // 8 KB
    const int bn = blockIdx.x, bm = blockIdx.y;
    const int tid = threadIdx.x;
    const int wave = tid >> 6, lane = tid & 63;
    const int wm = wave >> 1, wn = wave & 1;   // wave tile: 32 rows x 64 cols
    const int quad = lane >> 4, l16 = lane & 15;

    f32x4 acc[2][4] = {};

    // staging: A = 4 chunks of 1KB (wave w -> chunk w); B = 8 chunks (wave w -> 2w,2w+1)
    const int lr = lane >> 2, lc = (lane & 3) * 8;
    const __hip_bfloat16* Ag = A + (size_t)(bm * 64 + wave * 16 + lr) * K + lc;
    const int c0 = wave * 2, c1 = c0 + 1;
    const __hip_bfloat16* Bg0 = B + (size_t)(bn * 128 + c0 * 16 + lr) * K + lc;
    const __hip_bfloat16* Bg1 = B + (size_t)(bn * 128 + c1 * 16 + lr) * K + lc;
    __hip_bfloat16* lA = &At[wave * 512];
    __hip_bfloat16* lB0 = &Bt[c0 * 512];
    __hip_bfloat16* lB1 = &Bt[c1 * 512];

    for (int kt = 0; kt < K; kt += 32) {
        gl_lds16(Ag + kt, lA);
        gl_lds16(Bg0 + kt, lB0);
        gl_lds16(Bg1 + kt, lB1);
        __syncthreads();
        bf16x8 af[2], bfr[4];
#pragma unroll
        for (int i = 0; i < 2; ++i)
            af[i] = *(const bf16x8*)&At[(wm * 32 + i * 16 + l16) * 32 + quad * 8];
#pragma unroll
        for (int j = 0; j < 4; ++j)
            bfr[j] = *(const bf16x8*)&Bt[(wn * 64 + j * 16 + l16) * 32 + quad * 8];
#pragma unroll
        for (int i = 0; i < 2; ++i)
#pragma unroll
            for (int j = 0; j < 4; ++j) acc[i][j] = MFMA16(af[i], bfr[j], acc[i][j]);
        __syncthreads();
    }

    if (EPI == 0) {
        const int h = bn * 2 + wn;   // j*16+l16 < 64 -> h is j-independent
#pragma unroll
        for (int i = 0; i < 2; ++i) {
#pragma unroll
            for (int r = 0; r < 4; ++r) {
                const int mm = bm * 64 + wm * 32 + i * 16 + quad * 4 + r;  // token
                const int b = mm >> 11, n = mm & 2047;
                const size_t hb = (size_t)(b * 16 + h) * 131072;
                uint2 pk;
                pk.x = pk_bf16(acc[i][0][r], acc[i][1][r]);
                pk.y = pk_bf16(acc[i][2][r], acc[i][3][r]);
                // ztu: dh stored-permuted (4*l16 + j) -> one packed b64 store
                *(uint2*)(ztu + hb + n * 64 + l16 * 4) = pk;
                // ztut: rows = natural dh, cols = n permuted within 64-blocks
                const int np = (n & ~63) | (4 * (n & 15) + ((n >> 4) & 3));
                unsigned short* zt = ztut + hb + np;
                zt[(size_t)(0 * 16 + l16) * 2048] = (unsigned short)(pk.x & 0xffff);
                zt[(size_t)(1 * 16 + l16) * 2048] = (unsigned short)(pk.x >> 16);
                zt[(size_t)(2 * 16 + l16) * 2048] = (unsigned short)(pk.y & 0xffff);
                zt[(size_t)(3 * 16 + l16) * 2048] = (unsigned short)(pk.y >> 16);
            }
        }
    } else {
#pragma unroll
        for (int i = 0; i < 2; ++i) {
#pragma unroll
            for (int r = 0; r < 4; ++r) {
                const int mm = bm * 64 + wm * 32 + i * 16 + quad * 4 + r;
#pragma unroll
                for (int j = 0; j < 4; ++j) {
                    const int e = bn * 128 + wn * 64 + j * 16 + l16;
                    const float v = acc[i][j][r];
                    out0[(size_t)mm * 1024 + e] = v;
                    out1[(size_t)mm * 1024 + e] = v;
                }
            }
        }
    }
}

// ---------- flash attention ----------
// grid (16 qtiles, 32 bh), 512 threads = 8 waves; each wave owns 16 q-rows.
// K/V LDS tiles XOR-swizzled (group ^ row&7) -> conflict-free b128 reads.
// Fixed-max softmax: raw scores, p = v_exp_f32(s * DH^-.5 * log2e); per-lane
// partial sums, one cross-lane reduction in the epilogue.
__global__ __launch_bounds__(512, 4) void attn_k(const unsigned short* __restrict__ ztu,
                                                 const unsigned short* __restrict__ ztut,
                                                 unsigned short* __restrict__ ssa) {
    __shared__ __attribute__((aligned(16))) unsigned short Kt[64 * 64];   // [key][d-swizzled]
    __shared__ __attribute__((aligned(16))) unsigned short Vt[64 * 64];   // [d][key-swizzled]
    __shared__ __attribute__((aligned(16))) unsigned short Pt[8][16 * 72];  // per-wave P
    const int qt = blockIdx.x, bh = blockIdx.y;
    const int tid = threadIdx.x, wave = tid >> 6, lane = tid & 63;
    const int quad = lane >> 4, l16 = lane & 15;
    const unsigned short* base = ztu + (size_t)bh * 131072;
    const unsigned short* baseT = ztut + (size_t)bh * 131072;

    // Q fragments (raw, unscaled): A-layout m=l16, k=quad*8+j
    const int qb = qt * 128 + wave * 16;
    const bf16x8 qa0 = *(const bf16x8*)(base + (qb + l16) * 64 + quad * 8);
    const bf16x8 qa1 = *(const bf16x8*)(base + (qb + l16) * 64 + 32 + quad * 8);

    float lsum[4] = {};
    f32x4 o[4] = {};

    // staging: tile = 8 chunks of 1KB; wave w stages chunk w of K and of V.
    // chunk rows c*8+(lane>>3); swizzled source group = (lane&7)^(lane>>3)
    const int lrow = lane >> 3;
    const int sw = (lane & 7) ^ lrow;
    const unsigned short* gK = base + (wave * 8 + lrow) * 64 + sw * 8;
    const unsigned short* gV = baseT + (size_t)(wave * 8 + lrow) * 2048 + sw * 8;
    unsigned short* lK = &Kt[wave * 512];
    unsigned short* lV = &Vt[wave * 512];
    unsigned short* pw = &Pt[wave][0];

    // swizzled read offsets (elements)
    const int swq = (quad ^ (l16 & 7));
    const int koff0 = l16 * 64 + swq * 8;          // + {nf,df}*1024 per fragment row-group
    const int koff1 = l16 * 64 + (swq ^ 4) * 8;

    for (int t = 0; t < 32; ++t) {
        gl_lds16(gK + t * 4096, lK);
        gl_lds16(gV + t * 64, lV);
        __syncthreads();

        // S = Q * K^T  (16 q x 64 keys), C-layout col(key)=l16, row(q)=quad*4+r
        f32x4 s[4];
#pragma unroll
        for (int nf = 0; nf < 4; ++nf) {
            bf16x8 kb0 = *(const bf16x8*)&Kt[nf * 1024 + koff0];
            bf16x8 kb1 = *(const bf16x8*)&Kt[nf * 1024 + koff1];
            f32x4 z = {0.f, 0.f, 0.f, 0.f};
            z = MFMA16(qa0, kb0, z);
            z = MFMA16(qa1, kb1, z);
            s[nf] = z;
        }

        // p = exp2(s*QSCALE); per-lane partial sums; packed b64 LDS write.
        // P stored col = 4*l16 + nf  (matches ztut's key permutation)
#pragma unroll
        for (int r = 0; r < 4; ++r) {
            const float p0 = exp2_raw(s[0][r] * QSCALE);
            const float p1 = exp2_raw(s[1][r] * QSCALE);
            const float p2 = exp2_raw(s[2][r] * QSCALE);
            const float p3 = exp2_raw(s[3][r] * QSCALE);
            lsum[r] += (p0 + p1) + (p2 + p3);
            uint2 pk;
            pk.x = pk_bf16(p0, p1);
            pk.y = pk_bf16(p2, p3);
            *(uint2*)&pw[(quad * 4 + r) * 72 + l16 * 4] = pk;
        }
        asm volatile("s_waitcnt lgkmcnt(0)" ::: "memory");

        // O += P * V   (B-frag rows = d, swizzled key chunks)
        bf16x8 pa0 = *(const bf16x8*)&pw[l16 * 72 + quad * 8];
        bf16x8 pa1 = *(const bf16x8*)&pw[l16 * 72 + 32 + quad * 8];
#pragma unroll
        for (int df = 0; df < 4; ++df) {
            bf16x8 vb0 = *(const bf16x8*)&Vt[df * 1024 + koff0];
            bf16x8 vb1 = *(const bf16x8*)&Vt[df * 1024 + koff1];
            o[df] = MFMA16(pa0, vb0, o[df]);
            o[df] = MFMA16(pa1, vb1, o[df]);
        }
        __syncthreads();
    }

    // epilogue: reduce l across the 16 key-lanes, then packed b64 stores.
    // ssa stored col = h*64 + 4*l16 + df  (matches wtbf's e permutation)
    const int b = bh >> 4, h = bh & 15;
#pragma unroll
    for (int r = 0; r < 4; ++r) {
        float v = lsum[r];
        v += __shfl_xor(v, 1);
        v += __shfl_xor(v, 2);
        v += __shfl_xor(v, 4);
        v += __shfl_xor(v, 8);
        const float inv = 1.0f / v;
        const int token = b * 2048 + qt * 128 + wave * 16 + quad * 4 + r;
        uint2 pk;
        pk.x = pk_bf16(o[0][r] * inv, o[1][r] * inv);
        pk.y = pk_bf16(o[2][r] * inv, o[3][r] * inv);
        *(uint2*)(ssa + (size_t)token * 1024 + h * 64 + l16 * 4) = pk;
    }
}

// ---------- launch ----------
extern "C" void kernel_launch(void* const* d_in, const int* in_sizes, int n_in,
                              void* d_out, int out_size, void* d_ws, size_t ws_size,
                              hipStream_t stream) {
    const float* ZT = (const float*)d_in[0];  // (2,2048,1024)
    const float* W = (const float*)d_in[1];   // (1024,1024)
    float* out = (float*)d_out;               // 2 x 4194304 fp32
    char* ws = (char*)d_ws;

    unsigned short* ztbf  = (unsigned short*)(ws);                       // 8 MB
    unsigned short* wbf   = (unsigned short*)(ws + 8u * 1024 * 1024);    // 2 MB
    unsigned short* wtbf  = (unsigned short*)(ws + 10u * 1024 * 1024);   // 2 MB
    unsigned short* ztu   = (unsigned short*)(ws + 12u * 1024 * 1024);   // 8 MB (b,h,n,dh_perm)
    unsigned short* ztut  = (unsigned short*)(ws + 20u * 1024 * 1024);   // 8 MB (b,h,dh,n_perm)
    unsigned short* ssabf = (unsigned short*)(ws + 28u * 1024 * 1024);   // 8 MB (e_perm)

    cvt_k<<<5120, 256, 0, stream>>>(ZT, W, ztbf, wbf, wtbf);
    // ZTU = ZT @ W^T
    gemm_bt_k<0><<<dim3(8, 64), 256, 0, stream>>>((const __hip_bfloat16*)ztbf,
                                                  (const __hip_bfloat16*)wbf, 1024, ztu, ztut,
                                                  nullptr, nullptr);
    // flash attention per (bh, qtile of 128 rows), 8 waves/block
    attn_k<<<dim3(16, 32), 512, 0, stream>>>(ztu, ztut, ssabf);
    // mssa = ssa @ W, duplicated output
    gemm_bt_k<1><<<dim3(8, 64), 256, 0, stream>>>((const __hip_bfloat16*)ssabf,
                                                  (const __hip_bfloat16*)wtbf, 1024, nullptr,
                                                  nullptr, out, out + 4194304);
}